// Round 9
// baseline (379.742 us; speedup 1.0000x reference)
//
#include <hip/hip_runtime.h>
#include <hip/hip_bf16.h>

// Encoder layer. fp32 in/out, bf16 MFMA compute, fp32 accum.
// B=16 S=512 H=768 A=12 DH=64 F=3072.
// Round 9: fixes round 8's fused V-transpose head mapping. Faithful reshape:
// packed V elem (m,n) -> flat-in-batch fb=(m&511)*768+n; head a=fb>>15,
// s'=(fb>>6)&511, d=fb&63 (head slices straddle packed rows!). Round 8 used
// a=n/64 (the (B,S,A,DH) reshape) -> wrong op. Keeps flash Q-tile 128.

using bf16_t = __hip_bfloat16;
typedef __bf16 bf16x8 __attribute__((ext_vector_type(8)));
typedef float f32x4 __attribute__((ext_vector_type(4)));

__device__ __forceinline__ float b2f(bf16_t v) { return __bfloat162float(v); }
__device__ __forceinline__ bf16_t f2b(float v) { return __float2bfloat16(v); }
__device__ __forceinline__ ushort f2bu(float v) { bf16_t b = f2b(v); return *(ushort*)&b; }

// async global->LDS 16B copy (dest = wave base + lane*16 by construction)
__device__ __forceinline__ void glds16(const ushort* g, ushort* l) {
    __builtin_amdgcn_global_load_lds(
        (const __attribute__((address_space(1))) unsigned int*)g,
        (__attribute__((address_space(3))) unsigned int*)l, 16, 0, 0);
}

// tanh-form GELU (overflow-safe), |err vs exact| ~1e-3 << 0.102 threshold
__device__ __forceinline__ float gelu_f(float x) {
    float x2 = x * x;
    float y2 = 1.5957691216057308f * x * fmaf(0.044715f, x2, 1.0f);
    float e = __expf(y2);
    float t = 1.f - 2.f / (e + 1.f);
    return 0.5f * x * (1.f + t);
}

// ---------------------------------------------------------------------------
// Prep mega-kernel: 6 weight transposes + bias concat + X cast. One launch.
// ---------------------------------------------------------------------------
__device__ __forceinline__ void tr_tile(const float* __restrict__ in,
                                        bf16_t* __restrict__ out,
                                        int R, int C, int tx, int ty,
                                        float (*t)[65], int tid)
{
    int r0 = ty * 64, c0 = tx * 64;
    int tr = tid >> 6, tc = tid & 63;
#pragma unroll 4
    for (int i = 0; i < 16; ++i) {
        int r = i * 4 + tr;
        t[r][tc] = in[(size_t)(r0 + r) * C + c0 + tc];
    }
    __syncthreads();
#pragma unroll 4
    for (int i = 0; i < 16; ++i) {
        int r = i * 4 + tr;
        out[(size_t)(c0 + r) * R + r0 + tc] = f2b(t[tc][r]);
    }
}

__global__ __launch_bounds__(256) void prep_kernel(
    const float* __restrict__ WQ, const float* __restrict__ WK,
    const float* __restrict__ WV, const float* __restrict__ WO,
    const float* __restrict__ W1, const float* __restrict__ W2,
    const float* __restrict__ bQ, const float* __restrict__ bK,
    const float* __restrict__ bV, const float* __restrict__ X,
    bf16_t* __restrict__ Wqkv, bf16_t* __restrict__ WOt,
    bf16_t* __restrict__ W1t, bf16_t* __restrict__ W2t,
    float* __restrict__ bcat, bf16_t* __restrict__ Xb)
{
    __shared__ float t[64][65];
    const int blk = blockIdx.x, tid = threadIdx.x;
    if (blk < 576) {
        int m = blk / 144, tt = blk % 144;
        const float* in = (m == 0) ? WQ : (m == 1) ? WK : (m == 2) ? WV : WO;
        bf16_t* out = (m == 0) ? Wqkv : (m == 1) ? Wqkv + 589824
                    : (m == 2) ? Wqkv + 1179648 : WOt;
        tr_tile(in, out, 768, 768, tt % 12, tt / 12, t, tid);
    } else if (blk < 1152) {
        int tt = blk - 576;
        tr_tile(W1, W1t, 768, 3072, tt % 48, tt / 48, t, tid);
    } else if (blk < 1728) {
        int tt = blk - 1152;
        tr_tile(W2, W2t, 3072, 768, tt % 12, tt / 12, t, tid);
    } else if (blk == 1728) {
        for (int i = tid; i < 2304; i += 256)
            bcat[i] = (i < 768) ? bQ[i] : (i < 1536) ? bK[i - 768] : bV[i - 1536];
    } else {
        size_t i = ((size_t)(blk - 1729) * 256 + tid) * 8;
        float4 a = *(const float4*)(X + i);
        float4 b = *(const float4*)(X + i + 4);
#pragma unroll
        for (int j = 0; j < 4; ++j) {
            Xb[i + j]     = f2b(((const float*)&a)[j]);
            Xb[i + 4 + j] = f2b(((const float*)&b)[j]);
        }
    }
}

// ---------------------------------------------------------------------------
// NT GEMM, BK=64, swapped-operand MFMA: D layout lane=m-row, reg=4 consec n.
// Tile 128 x NTILE x 64, 256 thr = 4 waves; 32 MFMA/barrier at NTILE=128.
// Staging: global-side XOR swizzle (t&7)^(row&7); frag reads phys =
// (kk*4+quad)^(l16&7) -> 2 lanes/bank (free per m136).
// EPI: 0 bias->bf16 | 1 bias+GELU->bf16 | 2 bias+res(fp32,ld=ldc)->bf16
//      5 bias+res(bf16,ld=ldc)->fp32
//      6 bias, segmented: n/768 in {0,1} -> packed Qb/Kb; seg 2 -> Vt[h][d][s]
//        via FAITHFUL flat-reshape mapping (res carries the Vt pointer).
// ---------------------------------------------------------------------------
template <int EPI, int NTILE>
__global__ __launch_bounds__(256) void gemm128(
    const bf16_t* __restrict__ A, const bf16_t* __restrict__ Bt,
    const float* __restrict__ bias, const void* __restrict__ res,
    void* __restrict__ Cv, int K, int lda, int ldb, int ldc)
{
    __shared__ ushort lA[128 * 64];
    __shared__ ushort lB[NTILE * 64];
    constexpr int NI = NTILE / 32;
    const int tid = threadIdx.x;
    const int l = tid & 63, w = tid >> 6;
    const int l16 = l & 15, quad = l >> 4;
    const int m0 = blockIdx.x * 128, n0 = blockIdx.y * NTILE;

    const int srow = tid >> 3;
    const int sg = (((tid & 7) ^ (srow & 7)) << 3);
    const ushort* gA = (const ushort*)A + (size_t)(m0 + srow) * lda + sg;
    const ushort* gB = (const ushort*)Bt + (size_t)(n0 + srow) * ldb + sg;
    ushort* dA = lA + tid * 8;
    ushort* dB = lB + tid * 8;

    f32x4 acc[4][NI] = {};
    const int arow = (w & 1) * 64;
    const int brow = (w >> 1) * (NTILE / 2);

    for (int k0 = 0; k0 < K; k0 += 64) {
        __syncthreads();
        glds16(gA + k0,                      dA);
        glds16(gA + k0 + (size_t)32 * lda,   dA + 2048);
        glds16(gA + k0 + (size_t)64 * lda,   dA + 4096);
        glds16(gA + k0 + (size_t)96 * lda,   dA + 6144);
        glds16(gB + k0,                      dB);
        glds16(gB + k0 + (size_t)32 * ldb,   dB + 2048);
        if constexpr (NTILE == 128) {
            glds16(gB + k0 + (size_t)64 * ldb, dB + 4096);
            glds16(gB + k0 + (size_t)96 * ldb, dB + 6144);
        }
        __syncthreads();
#pragma unroll
        for (int kk = 0; kk < 2; ++kk) {
            const int pc = (((kk * 4 + quad) ^ (l16 & 7)) << 3);
            bf16x8 bfr[NI];
#pragma unroll
            for (int ni = 0; ni < NI; ++ni)
                bfr[ni] = *(const bf16x8*)&lB[(brow + ni * 16 + l16) * 64 + pc];
#pragma unroll
            for (int mi = 0; mi < 4; ++mi) {
                bf16x8 afr = *(const bf16x8*)&lA[(arow + mi * 16 + l16) * 64 + pc];
#pragma unroll
                for (int ni = 0; ni < NI; ++ni)   // SWAPPED: D lane=m, reg=n
                    acc[mi][ni] = __builtin_amdgcn_mfma_f32_16x16x32_bf16(bfr[ni], afr, acc[mi][ni], 0, 0, 0);
            }
        }
    }

    float4 bv4[NI];
#pragma unroll
    for (int ni = 0; ni < NI; ++ni)
        bv4[ni] = *(const float4*)&bias[n0 + brow + ni * 16 + quad * 4];

#pragma unroll
    for (int mi = 0; mi < 4; ++mi) {
        int m = m0 + arow + mi * 16 + l16;
#pragma unroll
        for (int ni = 0; ni < NI; ++ni) {
            int nb = n0 + brow + ni * 16 + quad * 4;   // 4 consecutive n
            float v[4];
#pragma unroll
            for (int r = 0; r < 4; ++r) v[r] = acc[mi][ni][r] + ((const float*)&bv4[ni])[r];
            if constexpr (EPI == 1) {
#pragma unroll
                for (int r = 0; r < 4; ++r) v[r] = gelu_f(v[r]);
            } else if constexpr (EPI == 2) {
                float4 r4 = *(const float4*)&((const float*)res)[(size_t)m * ldc + nb];
#pragma unroll
                for (int r = 0; r < 4; ++r) v[r] += ((const float*)&r4)[r];
            } else if constexpr (EPI == 5) {
                ushort4 rb = *(const ushort4*)&((const ushort*)res)[(size_t)m * ldc + nb];
#pragma unroll
                for (int r = 0; r < 4; ++r) v[r] += b2f(*(const bf16_t*)&((const ushort*)&rb)[r]);
            }
            if constexpr (EPI == 5) {
                *(float4*)&((float*)Cv)[(size_t)m * ldc + nb] = make_float4(v[0], v[1], v[2], v[3]);
            } else {
                ushort4 st;
                st.x = f2bu(v[0]); st.y = f2bu(v[1]); st.z = f2bu(v[2]); st.w = f2bu(v[3]);
                if constexpr (EPI == 6) {
                    int seg = n0 / 768;      // block-uniform (768 % NTILE == 0)
                    if (seg < 2) {
                        bf16_t* Cseg = (bf16_t*)Cv + (size_t)seg * 6291456;
                        int nloc = (n0 % 768) + brow + ni * 16 + quad * 4;
                        *(ushort4*)&((ushort*)Cseg)[(size_t)m * 768 + nloc] = st;
                    } else {
                        // V segment -> Vt[h][d][s'] via faithful flat reshape:
                        // fb = (m&511)*768 + nloc; a = fb>>15; s' = (fb>>6)&511;
                        // d = fb&63. (fb%64 == nloc%64 since 768%64==0, so the
                        // 4 consecutive n's stay 4 consecutive d's, same h,s'.)
                        ushort* vt = (ushort*)res;
                        int nloc = (n0 - 1536) + brow + ni * 16 + quad * 4;
                        int fb = (m & 511) * 768 + nloc;
                        int h = (m >> 9) * 12 + (fb >> 15);
                        int d = fb & 63;
                        int s = (fb >> 6) & 511;
                        ushort* vh = vt + (size_t)h * 32768 + s;
                        vh[(size_t)(d + 0) * 512] = st.x;
                        vh[(size_t)(d + 1) * 512] = st.y;
                        vh[(size_t)(d + 2) * 512] = st.z;
                        vh[(size_t)(d + 3) * 512] = st.w;
                    }
                } else {
                    *(ushort4*)&((ushort*)Cv)[(size_t)m * ldc + nb] = st;
                }
            }
        }
    }
}

// ---------------------------------------------------------------------------
// Flash attention, Q-tile 128, swapped-operand MFMA (round-7 verified layout,
// generalized by mi over 2 q-subtiles per wave). One block = (q-tile 128, head).
// Wave w owns q rows w*32 + mi*16 + l16. S=512 D=64, 8 K-tiles; per-lane
// scalar softmax state per mi; P via lP[128][72]; Z in-place over Q.
// ---------------------------------------------------------------------------
__global__ __launch_bounds__(256) void flash_kernel(
    const bf16_t* __restrict__ Q, const bf16_t* __restrict__ Kx,
    const bf16_t* __restrict__ Vt, const int* __restrict__ mask,
    bf16_t* __restrict__ Z)
{
    __shared__ ushort lK[64 * 64];
    __shared__ ushort lV[64 * 64];
    __shared__ ushort lP[128 * 72];

    const int h = blockIdx.y;
    const int q0 = blockIdx.x * 128;
    const ushort* Qh = (const ushort*)Q + (size_t)h * 32768;
    const ushort* Kh = (const ushort*)Kx + (size_t)h * 32768;
    const ushort* Vh = (const ushort*)Vt + (size_t)h * 32768;   // [64][512]
    const int* mk = mask + (h / 12) * 512;
    ushort* Zh = (ushort*)Z + (size_t)h * 32768;

    const int tid = threadIdx.x;
    const int l = tid & 63, w = tid >> 6;
    const int l16 = l & 15, quad = l >> 4;

    bf16x8 qfr[2][2];   // [mi][kk]
#pragma unroll
    for (int mi = 0; mi < 2; ++mi)
#pragma unroll
        for (int kk = 0; kk < 2; ++kk)
            qfr[mi][kk] = *(const bf16x8*)(Qh + (size_t)(q0 + w * 32 + mi * 16 + l16) * 64 + kk * 32 + quad * 8);

    const int c8p = tid & 7;
    const int kr0 = tid >> 3;
    float m_i[2] = {-1e30f, -1e30f}, l_i[2] = {0.f, 0.f};
    f32x4 o4[2][4] = {};

    for (int kt = 0; kt < 8; ++kt) {
#pragma unroll
        for (int p = 0; p < 2; ++p) {
            int row = kr0 + p * 32;
            int c8l = c8p ^ (row & 7);
            glds16(Kh + (size_t)(kt * 64 + row) * 64 + c8l * 8, lK + (p * 256 + tid) * 8);
            glds16(Vh + (size_t)row * 512 + kt * 64 + c8l * 8, lV + (p * 256 + tid) * 8);
        }
        __syncthreads();

        f32x4 s4[2][4] = {};
#pragma unroll
        for (int kk = 0; kk < 2; ++kk) {
#pragma unroll
            for (int nt = 0; nt < 4; ++nt) {
                bf16x8 kfr = *(const bf16x8*)&lK[(nt * 16 + l16) * 64 + (((kk * 4 + quad) ^ (l16 & 7)) << 3)];
#pragma unroll
                for (int mi = 0; mi < 2; ++mi)
                    s4[mi][nt] = __builtin_amdgcn_mfma_f32_16x16x32_bf16(kfr, qfr[mi][kk], s4[mi][nt], 0, 0, 0);
            }
        }

        int4 m4[4];
#pragma unroll
        for (int nt = 0; nt < 4; ++nt) m4[nt] = *(const int4*)&mk[kt * 64 + nt * 16 + quad * 4];

#pragma unroll
        for (int mi = 0; mi < 2; ++mi) {
            float pv[4][4];
            float rm = -1e30f;
#pragma unroll
            for (int nt = 0; nt < 4; ++nt)
#pragma unroll
                for (int r = 0; r < 4; ++r) {
                    float v = (((const int*)&m4[nt])[r] == 0) ? -1e30f : s4[mi][nt][r] * 0.125f;
                    pv[nt][r] = v;
                    rm = fmaxf(rm, v);
                }
            rm = fmaxf(rm, __shfl_xor(rm, 16));
            rm = fmaxf(rm, __shfl_xor(rm, 32));
            float mn = fmaxf(m_i[mi], rm);
            float al = __expf(m_i[mi] - mn);
            float rs = 0.f;
#pragma unroll
            for (int nt = 0; nt < 4; ++nt)
#pragma unroll
                for (int r = 0; r < 4; ++r) {
                    float e = __expf(pv[nt][r] - mn);
                    pv[nt][r] = e;
                    rs += e;
                }
            rs += __shfl_xor(rs, 16);
            rs += __shfl_xor(rs, 32);
            l_i[mi] = l_i[mi] * al + rs;
            m_i[mi] = mn;
#pragma unroll
            for (int dt = 0; dt < 4; ++dt)
#pragma unroll
                for (int r = 0; r < 4; ++r) o4[mi][dt][r] *= al;

#pragma unroll
            for (int nt = 0; nt < 4; ++nt) {
                ushort4 st;
                st.x = f2bu(pv[nt][0]); st.y = f2bu(pv[nt][1]);
                st.z = f2bu(pv[nt][2]); st.w = f2bu(pv[nt][3]);
                *(ushort4*)&lP[(w * 32 + mi * 16 + l16) * 72 + nt * 16 + quad * 4] = st;
            }
        }
        __syncthreads();

#pragma unroll
        for (int kk = 0; kk < 2; ++kk) {
#pragma unroll
            for (int dt = 0; dt < 4; ++dt) {
                bf16x8 bvfr = *(const bf16x8*)&lV[(dt * 16 + l16) * 64 + (((kk * 4 + quad) ^ (l16 & 7)) << 3)];
#pragma unroll
                for (int mi = 0; mi < 2; ++mi) {
                    bf16x8 pafr = *(const bf16x8*)&lP[(w * 32 + mi * 16 + l16) * 72 + kk * 32 + quad * 8];
                    o4[mi][dt] = __builtin_amdgcn_mfma_f32_16x16x32_bf16(bvfr, pafr, o4[mi][dt], 0, 0, 0);
                }
            }
        }
        __syncthreads();
    }

#pragma unroll
    for (int mi = 0; mi < 2; ++mi) {
        float inv = 1.f / l_i[mi];
#pragma unroll
        for (int dt = 0; dt < 4; ++dt) {
            ushort4 st;
            st.x = f2bu(o4[mi][dt][0] * inv); st.y = f2bu(o4[mi][dt][1] * inv);
            st.z = f2bu(o4[mi][dt][2] * inv); st.w = f2bu(o4[mi][dt][3] * inv);
            *(ushort4*)&Zh[(size_t)(q0 + w * 32 + mi * 16 + l16) * 64 + dt * 16 + quad * 4] = st;
        }
    }
}

// ---------------------------------------------------------------------------
// LayerNorm over H=768, one block per row, fp32 stats. In-place safe.
// ---------------------------------------------------------------------------
__device__ __forceinline__ float to_f(float v)  { return v; }
__device__ __forceinline__ float to_f(bf16_t v) { return b2f(v); }
__device__ __forceinline__ void from_f(float& d, float v)  { d = v; }
__device__ __forceinline__ void from_f(bf16_t& d, float v) { d = f2b(v); }

template <typename TI, typename TO>
__global__ __launch_bounds__(256) void layernorm_kernel(
    const TI* __restrict__ X, const float* __restrict__ w,
    const float* __restrict__ b, TO* __restrict__ out)
{
    const TI* x = X + (size_t)blockIdx.x * 768;
    TO* o = out + (size_t)blockIdx.x * 768;
    int t = threadIdx.x;
    float v[3];
    float s = 0.f, sq = 0.f;
#pragma unroll
    for (int i = 0; i < 3; ++i) {
        v[i] = to_f(x[t + i * 256]);
        s += v[i]; sq += v[i] * v[i];
    }
#pragma unroll
    for (int off = 32; off; off >>= 1) { s += __shfl_xor(s, off); sq += __shfl_xor(sq, off); }
    __shared__ float s1[4], s2[4];
    int wave = t >> 6, lane = t & 63;
    if (lane == 0) { s1[wave] = s; s2[wave] = sq; }
    __syncthreads();
    s  = s1[0] + s1[1] + s1[2] + s1[3];
    sq = s2[0] + s2[1] + s2[2] + s2[3];
    float mu  = s * (1.f / 768.f);
    float var = sq * (1.f / 768.f) - mu * mu;
    float rs  = rsqrtf(var + 1e-5f);
#pragma unroll
    for (int i = 0; i < 3; ++i)
        from_f(o[t + i * 256], (v[i] - mu) * rs * w[t + i * 256] + b[t + i * 256]);
}

// ---------------------------------------------------------------------------
extern "C" void kernel_launch(void* const* d_in, const int* in_sizes, int n_in,
                              void* d_out, int out_size, void* d_ws, size_t ws_size,
                              hipStream_t stream)
{
    const float* X    = (const float*)d_in[0];
    const int*   mask = (const int*)  d_in[1];
    const float* WQ   = (const float*)d_in[2];
    const float* bQ   = (const float*)d_in[3];
    const float* WK   = (const float*)d_in[4];
    const float* bK   = (const float*)d_in[5];
    const float* WV   = (const float*)d_in[6];
    const float* bV   = (const float*)d_in[7];
    const float* WO   = (const float*)d_in[8];
    const float* bO   = (const float*)d_in[9];
    const float* ln1w = (const float*)d_in[10];
    const float* ln1b = (const float*)d_in[11];
    const float* W1   = (const float*)d_in[12];
    const float* b1   = (const float*)d_in[13];
    const float* W2   = (const float*)d_in[14];
    const float* b2   = (const float*)d_in[15];
    const float* ln2w = (const float*)d_in[16];
    const float* ln2b = (const float*)d_in[17];
    float* out = (float*)d_out;

    // ---- workspace (bf16 elems; total 38,539,776 = 77.1 MB) ----
    bf16_t* ws   = (bf16_t*)d_ws;
    bf16_t* Wqkv = ws;                        // [2304][768] (WQt|WKt|WVt)
    bf16_t* WOt  = Wqkv + 1769472;            // [768][768]
    bf16_t* W1t  = WOt + 589824;              // [3072][768]
    bf16_t* W2t  = W1t + 2359296;             // [768][3072]
    float*  bcat = (float*)(W2t + 2359296);   // fp32[2304] (= 4608 bf16)
    bf16_t* Qb   = W2t + 2359296 + 4608;      // packed [8192][768]; Q,K consecutive (EPI 6)
    bf16_t* Kb   = Qb + 6291456;
    bf16_t* Vb   = Kb + 6291456;              // (unused this round; kept for layout)
    bf16_t* Xb   = Vb + 6291456;              // bf16 X (dead after QKV; Y1 alias)
    bf16_t* Vt   = Xb + 6291456;              // per-head V^T [192][64][512], written by QKV epilogue
    // aliases (dead-before-write):
    bf16_t* Zb = Qb;   // flash writes Z in-place over Q
    bf16_t* Y1 = Xb;   // O-proj out (Xb dead after QKV gemm)
    bf16_t* X1 = Qb;   // LN1 out (Qb/Z dead after O-proj)
    bf16_t* Hb = Kb;   // FFN mid [8192][3072] = Kb+Vb+Xb+Vt exactly

    // ---- 1. prep ----
    prep_kernel<<<4801, 256, 0, stream>>>(WQ, WK, WV, WO, W1, W2, bQ, bK, bV, X,
                                          Wqkv, WOt, W1t, W2t, bcat, Xb);

    // ---- 2. fused QKV projection -> packed Q/K + transposed Vt ----
    gemm128<6, 128><<<dim3(64, 18), 256, 0, stream>>>(Xb, Wqkv, bcat, Vt, Qb,
                                                      768, 768, 768, 768);

    // ---- 3. flash attention (Q-tile 128), Z in-place over Q ----
    flash_kernel<<<dim3(4, 192), 256, 0, stream>>>(Qb, Kb, Vt, mask, Zb);

    // ---- 4. O-projection + fp32 residual -> Y1, LN1 -> X1 ----
    gemm128<2, 64><<<dim3(64, 12), 256, 0, stream>>>(Zb, WOt, bO, X, Y1,
                                                     768, 768, 768, 768);
    layernorm_kernel<bf16_t, bf16_t><<<8192, 256, 0, stream>>>(Y1, ln1w, ln1b, X1);

    // ---- 5. FFN ----
    gemm128<1, 128><<<dim3(64, 24), 256, 0, stream>>>(X1, W1t, b1, nullptr, Hb,
                                                      768, 768, 768, 3072);
    gemm128<5, 64><<<dim3(64, 12), 256, 0, stream>>>(Hb, W2t, b2, X1, out,
                                                     3072, 3072, 3072, 768);
    layernorm_kernel<float, float><<<8192, 256, 0, stream>>>(out, ln2w, ln2b, out);
}

// Round 10
// 364.677 us; speedup vs baseline: 1.0413x; 1.0413x over previous
//
#include <hip/hip_runtime.h>
#include <hip/hip_bf16.h>

// Encoder layer. fp32 in/out, bf16 MFMA compute, fp32 accum.
// B=16 S=512 H=768 A=12 DH=64 F=3072.
// Round 10: GEMM K-loop switched to mfma_f32_32x32x16_bf16 (swapped operands).
// m119: 32x32 = 2495 TF vs 16x16 2176 -> 17% less matrix-pipe time, half the
// MFMA instruction count per K-iter (16 vs 32), same 16 ds_read_b128/iter.
// C/D (verified m74/m101): col=lane&31, row=(reg&3)+8(reg>>2)+4(lane>>5) ->
// swapped gives lane=m, each f32x4 reg group = 4 consecutive n (vector epi).
// Flash (Q-tile 128) and fused V-transpose unchanged from round 9.

using bf16_t = __hip_bfloat16;
typedef __bf16 bf16x8 __attribute__((ext_vector_type(8)));
typedef float f32x4 __attribute__((ext_vector_type(4)));
typedef float f32x16 __attribute__((ext_vector_type(16)));

__device__ __forceinline__ float b2f(bf16_t v) { return __bfloat162float(v); }
__device__ __forceinline__ bf16_t f2b(float v) { return __float2bfloat16(v); }
__device__ __forceinline__ ushort f2bu(float v) { bf16_t b = f2b(v); return *(ushort*)&b; }

// async global->LDS 16B copy (dest = wave base + lane*16 by construction)
__device__ __forceinline__ void glds16(const ushort* g, ushort* l) {
    __builtin_amdgcn_global_load_lds(
        (const __attribute__((address_space(1))) unsigned int*)g,
        (__attribute__((address_space(3))) unsigned int*)l, 16, 0, 0);
}

// tanh-form GELU (overflow-safe), |err vs exact| ~1e-3 << 0.102 threshold
__device__ __forceinline__ float gelu_f(float x) {
    float x2 = x * x;
    float y2 = 1.5957691216057308f * x * fmaf(0.044715f, x2, 1.0f);
    float e = __expf(y2);
    float t = 1.f - 2.f / (e + 1.f);
    return 0.5f * x * (1.f + t);
}

// ---------------------------------------------------------------------------
// Prep mega-kernel: 6 weight transposes + bias concat + X cast. One launch.
// ---------------------------------------------------------------------------
__device__ __forceinline__ void tr_tile(const float* __restrict__ in,
                                        bf16_t* __restrict__ out,
                                        int R, int C, int tx, int ty,
                                        float (*t)[65], int tid)
{
    int r0 = ty * 64, c0 = tx * 64;
    int tr = tid >> 6, tc = tid & 63;
#pragma unroll 4
    for (int i = 0; i < 16; ++i) {
        int r = i * 4 + tr;
        t[r][tc] = in[(size_t)(r0 + r) * C + c0 + tc];
    }
    __syncthreads();
#pragma unroll 4
    for (int i = 0; i < 16; ++i) {
        int r = i * 4 + tr;
        out[(size_t)(c0 + r) * R + r0 + tc] = f2b(t[tc][r]);
    }
}

__global__ __launch_bounds__(256) void prep_kernel(
    const float* __restrict__ WQ, const float* __restrict__ WK,
    const float* __restrict__ WV, const float* __restrict__ WO,
    const float* __restrict__ W1, const float* __restrict__ W2,
    const float* __restrict__ bQ, const float* __restrict__ bK,
    const float* __restrict__ bV, const float* __restrict__ X,
    bf16_t* __restrict__ Wqkv, bf16_t* __restrict__ WOt,
    bf16_t* __restrict__ W1t, bf16_t* __restrict__ W2t,
    float* __restrict__ bcat, bf16_t* __restrict__ Xb)
{
    __shared__ float t[64][65];
    const int blk = blockIdx.x, tid = threadIdx.x;
    if (blk < 576) {
        int m = blk / 144, tt = blk % 144;
        const float* in = (m == 0) ? WQ : (m == 1) ? WK : (m == 2) ? WV : WO;
        bf16_t* out = (m == 0) ? Wqkv : (m == 1) ? Wqkv + 589824
                    : (m == 2) ? Wqkv + 1179648 : WOt;
        tr_tile(in, out, 768, 768, tt % 12, tt / 12, t, tid);
    } else if (blk < 1152) {
        int tt = blk - 576;
        tr_tile(W1, W1t, 768, 3072, tt % 48, tt / 48, t, tid);
    } else if (blk < 1728) {
        int tt = blk - 1152;
        tr_tile(W2, W2t, 3072, 768, tt % 12, tt / 12, t, tid);
    } else if (blk == 1728) {
        for (int i = tid; i < 2304; i += 256)
            bcat[i] = (i < 768) ? bQ[i] : (i < 1536) ? bK[i - 768] : bV[i - 1536];
    } else {
        size_t i = ((size_t)(blk - 1729) * 256 + tid) * 8;
        float4 a = *(const float4*)(X + i);
        float4 b = *(const float4*)(X + i + 4);
#pragma unroll
        for (int j = 0; j < 4; ++j) {
            Xb[i + j]     = f2b(((const float*)&a)[j]);
            Xb[i + 4 + j] = f2b(((const float*)&b)[j]);
        }
    }
}

// ---------------------------------------------------------------------------
// NT GEMM, BK=64, swapped-operand mfma_f32_32x32x16_bf16.
// Tile 128 x NTILE x 64, 256 thr = 4 waves; wave quadrant 64 x (NTILE/2) =
// 2x(NTILE/64) subtiles of 32x32. Per K-iter: 4 kk-steps (K=16 each),
// 16 MFMA at NTILE=128 (vs 32 with 16x16), same 16 ds_read_b128.
// Frags: row = lane&31, k = kk*16 + (lane>>5)*8; phys chunk =
// (kk*2 + (lane>>5)) ^ (row&7) -> 2 lanes/bank per 16-lane phase (free, m136).
// D (swapped): lane = m-row; reg g*4+r -> n = 8g + 4*(lane>>5) + r (4 consec).
// EPI: 0 bias->bf16 | 1 bias+GELU->bf16 | 2 bias+res(fp32,ld=ldc)->bf16
//      5 bias+res(bf16,ld=ldc)->fp32
//      6 bias, segmented: n/768 in {0,1} -> packed Qb/Kb; seg 2 -> Vt[h][d][s']
//        via faithful flat reshape (res carries the Vt pointer).
// ---------------------------------------------------------------------------
template <int EPI, int NTILE>
__global__ __launch_bounds__(256) void gemm128(
    const bf16_t* __restrict__ A, const bf16_t* __restrict__ Bt,
    const float* __restrict__ bias, const void* __restrict__ res,
    void* __restrict__ Cv, int K, int lda, int ldb, int ldc)
{
    __shared__ ushort lA[128 * 64];
    __shared__ ushort lB[NTILE * 64];
    constexpr int NI = NTILE / 64;           // 32x32 n-subtiles per wave
    const int tid = threadIdx.x;
    const int l = tid & 63, w = tid >> 6;
    const int l31 = l & 31, khalf = l >> 5;  // frag row / k-half
    const int m0 = blockIdx.x * 128, n0 = blockIdx.y * NTILE;

    const int srow = tid >> 3;
    const int sg = (((tid & 7) ^ (srow & 7)) << 3);
    const ushort* gA = (const ushort*)A + (size_t)(m0 + srow) * lda + sg;
    const ushort* gB = (const ushort*)Bt + (size_t)(n0 + srow) * ldb + sg;
    ushort* dA = lA + tid * 8;
    ushort* dB = lB + tid * 8;

    f32x16 acc[2][NI] = {};
    const int arow = (w & 1) * 64;
    const int brow = (w >> 1) * (NTILE / 2);

    for (int k0 = 0; k0 < K; k0 += 64) {
        __syncthreads();
        glds16(gA + k0,                      dA);
        glds16(gA + k0 + (size_t)32 * lda,   dA + 2048);
        glds16(gA + k0 + (size_t)64 * lda,   dA + 4096);
        glds16(gA + k0 + (size_t)96 * lda,   dA + 6144);
        glds16(gB + k0,                      dB);
        glds16(gB + k0 + (size_t)32 * ldb,   dB + 2048);
        if constexpr (NTILE == 128) {
            glds16(gB + k0 + (size_t)64 * ldb, dB + 4096);
            glds16(gB + k0 + (size_t)96 * ldb, dB + 6144);
        }
        __syncthreads();
#pragma unroll
        for (int kk = 0; kk < 4; ++kk) {
            const int pc = (((kk * 2 + khalf) ^ (l31 & 7)) << 3);
            bf16x8 bfr[NI];
#pragma unroll
            for (int ni = 0; ni < NI; ++ni)
                bfr[ni] = *(const bf16x8*)&lB[(brow + ni * 32 + l31) * 64 + pc];
#pragma unroll
            for (int mi = 0; mi < 2; ++mi) {
                bf16x8 afr = *(const bf16x8*)&lA[(arow + mi * 32 + l31) * 64 + pc];
#pragma unroll
                for (int ni = 0; ni < NI; ++ni)   // SWAPPED: D lane=m, regs=n
                    acc[mi][ni] = __builtin_amdgcn_mfma_f32_32x32x16_bf16(bfr[ni], afr, acc[mi][ni], 0, 0, 0);
            }
        }
    }

    // Epilogue: m = arow + mi*32 + l31; reg g*4+r -> n = ni*32 + 8g + 4*khalf + r
#pragma unroll
    for (int mi = 0; mi < 2; ++mi) {
        int m = m0 + arow + mi * 32 + l31;
#pragma unroll
        for (int ni = 0; ni < NI; ++ni) {
#pragma unroll
            for (int g = 0; g < 4; ++g) {
                int nb = n0 + brow + ni * 32 + 8 * g + 4 * khalf;  // 4 consecutive n
                float4 bv4 = *(const float4*)&bias[nb];
                float v[4];
#pragma unroll
                for (int r = 0; r < 4; ++r) v[r] = acc[mi][ni][g * 4 + r] + ((const float*)&bv4)[r];
                if constexpr (EPI == 1) {
#pragma unroll
                    for (int r = 0; r < 4; ++r) v[r] = gelu_f(v[r]);
                } else if constexpr (EPI == 2) {
                    float4 r4 = *(const float4*)&((const float*)res)[(size_t)m * ldc + nb];
#pragma unroll
                    for (int r = 0; r < 4; ++r) v[r] += ((const float*)&r4)[r];
                } else if constexpr (EPI == 5) {
                    ushort4 rb = *(const ushort4*)&((const ushort*)res)[(size_t)m * ldc + nb];
#pragma unroll
                    for (int r = 0; r < 4; ++r) v[r] += b2f(*(const bf16_t*)&((const ushort*)&rb)[r]);
                }
                if constexpr (EPI == 5) {
                    *(float4*)&((float*)Cv)[(size_t)m * ldc + nb] = make_float4(v[0], v[1], v[2], v[3]);
                } else {
                    ushort4 st;
                    st.x = f2bu(v[0]); st.y = f2bu(v[1]); st.z = f2bu(v[2]); st.w = f2bu(v[3]);
                    if constexpr (EPI == 6) {
                        int seg = n0 / 768;      // block-uniform (768 % NTILE == 0)
                        int nloc = (n0 % 768) + brow + ni * 32 + 8 * g + 4 * khalf;
                        if (seg < 2) {
                            bf16_t* Cseg = (bf16_t*)Cv + (size_t)seg * 6291456;
                            *(ushort4*)&((ushort*)Cseg)[(size_t)m * 768 + nloc] = st;
                        } else {
                            // V segment -> Vt[h][d][s'] via faithful flat reshape:
                            // fb = (m&511)*768 + nloc; a=fb>>15; s'=(fb>>6)&511; d=fb&63.
                            ushort* vt = (ushort*)res;
                            int fb = (m & 511) * 768 + nloc;
                            int h = (m >> 9) * 12 + (fb >> 15);
                            int d = fb & 63;
                            int s = (fb >> 6) & 511;
                            ushort* vh = vt + (size_t)h * 32768 + s;
                            vh[(size_t)(d + 0) * 512] = st.x;
                            vh[(size_t)(d + 1) * 512] = st.y;
                            vh[(size_t)(d + 2) * 512] = st.z;
                            vh[(size_t)(d + 3) * 512] = st.w;
                        }
                    } else {
                        *(ushort4*)&((ushort*)Cv)[(size_t)m * ldc + nb] = st;
                    }
                }
            }
        }
    }
}

// ---------------------------------------------------------------------------
// Flash attention, Q-tile 128, swapped-operand 16x16x32 MFMA (round-9 verified).
// One block = (q-tile 128, head). Wave w owns q rows w*32 + mi*16 + l16.
// S=512 D=64, 8 K-tiles; per-lane scalar softmax state per mi; P via
// lP[128][72]; Z in-place over Q.
// ---------------------------------------------------------------------------
__global__ __launch_bounds__(256) void flash_kernel(
    const bf16_t* __restrict__ Q, const bf16_t* __restrict__ Kx,
    const bf16_t* __restrict__ Vt, const int* __restrict__ mask,
    bf16_t* __restrict__ Z)
{
    __shared__ ushort lK[64 * 64];
    __shared__ ushort lV[64 * 64];
    __shared__ ushort lP[128 * 72];

    const int h = blockIdx.y;
    const int q0 = blockIdx.x * 128;
    const ushort* Qh = (const ushort*)Q + (size_t)h * 32768;
    const ushort* Kh = (const ushort*)Kx + (size_t)h * 32768;
    const ushort* Vh = (const ushort*)Vt + (size_t)h * 32768;   // [64][512]
    const int* mk = mask + (h / 12) * 512;
    ushort* Zh = (ushort*)Z + (size_t)h * 32768;

    const int tid = threadIdx.x;
    const int l = tid & 63, w = tid >> 6;
    const int l16 = l & 15, quad = l >> 4;

    bf16x8 qfr[2][2];   // [mi][kk]
#pragma unroll
    for (int mi = 0; mi < 2; ++mi)
#pragma unroll
        for (int kk = 0; kk < 2; ++kk)
            qfr[mi][kk] = *(const bf16x8*)(Qh + (size_t)(q0 + w * 32 + mi * 16 + l16) * 64 + kk * 32 + quad * 8);

    const int c8p = tid & 7;
    const int kr0 = tid >> 3;
    float m_i[2] = {-1e30f, -1e30f}, l_i[2] = {0.f, 0.f};
    f32x4 o4[2][4] = {};

    for (int kt = 0; kt < 8; ++kt) {
#pragma unroll
        for (int p = 0; p < 2; ++p) {
            int row = kr0 + p * 32;
            int c8l = c8p ^ (row & 7);
            glds16(Kh + (size_t)(kt * 64 + row) * 64 + c8l * 8, lK + (p * 256 + tid) * 8);
            glds16(Vh + (size_t)row * 512 + kt * 64 + c8l * 8, lV + (p * 256 + tid) * 8);
        }
        __syncthreads();

        f32x4 s4[2][4] = {};
#pragma unroll
        for (int kk = 0; kk < 2; ++kk) {
#pragma unroll
            for (int nt = 0; nt < 4; ++nt) {
                bf16x8 kfr = *(const bf16x8*)&lK[(nt * 16 + l16) * 64 + (((kk * 4 + quad) ^ (l16 & 7)) << 3)];
#pragma unroll
                for (int mi = 0; mi < 2; ++mi)
                    s4[mi][nt] = __builtin_amdgcn_mfma_f32_16x16x32_bf16(kfr, qfr[mi][kk], s4[mi][nt], 0, 0, 0);
            }
        }

        int4 m4[4];
#pragma unroll
        for (int nt = 0; nt < 4; ++nt) m4[nt] = *(const int4*)&mk[kt * 64 + nt * 16 + quad * 4];

#pragma unroll
        for (int mi = 0; mi < 2; ++mi) {
            float pv[4][4];
            float rm = -1e30f;
#pragma unroll
            for (int nt = 0; nt < 4; ++nt)
#pragma unroll
                for (int r = 0; r < 4; ++r) {
                    float v = (((const int*)&m4[nt])[r] == 0) ? -1e30f : s4[mi][nt][r] * 0.125f;
                    pv[nt][r] = v;
                    rm = fmaxf(rm, v);
                }
            rm = fmaxf(rm, __shfl_xor(rm, 16));
            rm = fmaxf(rm, __shfl_xor(rm, 32));
            float mn = fmaxf(m_i[mi], rm);
            float al = __expf(m_i[mi] - mn);
            float rs = 0.f;
#pragma unroll
            for (int nt = 0; nt < 4; ++nt)
#pragma unroll
                for (int r = 0; r < 4; ++r) {
                    float e = __expf(pv[nt][r] - mn);
                    pv[nt][r] = e;
                    rs += e;
                }
            rs += __shfl_xor(rs, 16);
            rs += __shfl_xor(rs, 32);
            l_i[mi] = l_i[mi] * al + rs;
            m_i[mi] = mn;
#pragma unroll
            for (int dt = 0; dt < 4; ++dt)
#pragma unroll
                for (int r = 0; r < 4; ++r) o4[mi][dt][r] *= al;

#pragma unroll
            for (int nt = 0; nt < 4; ++nt) {
                ushort4 st;
                st.x = f2bu(pv[nt][0]); st.y = f2bu(pv[nt][1]);
                st.z = f2bu(pv[nt][2]); st.w = f2bu(pv[nt][3]);
                *(ushort4*)&lP[(w * 32 + mi * 16 + l16) * 72 + nt * 16 + quad * 4] = st;
            }
        }
        __syncthreads();

#pragma unroll
        for (int kk = 0; kk < 2; ++kk) {
#pragma unroll
            for (int dt = 0; dt < 4; ++dt) {
                bf16x8 bvfr = *(const bf16x8*)&lV[(dt * 16 + l16) * 64 + (((kk * 4 + quad) ^ (l16 & 7)) << 3)];
#pragma unroll
                for (int mi = 0; mi < 2; ++mi) {
                    bf16x8 pafr = *(const bf16x8*)&lP[(w * 32 + mi * 16 + l16) * 72 + kk * 32 + quad * 8];
                    o4[mi][dt] = __builtin_amdgcn_mfma_f32_16x16x32_bf16(bvfr, pafr, o4[mi][dt], 0, 0, 0);
                }
            }
        }
        __syncthreads();
    }

#pragma unroll
    for (int mi = 0; mi < 2; ++mi) {
        float inv = 1.f / l_i[mi];
#pragma unroll
        for (int dt = 0; dt < 4; ++dt) {
            ushort4 st;
            st.x = f2bu(o4[mi][dt][0] * inv); st.y = f2bu(o4[mi][dt][1] * inv);
            st.z = f2bu(o4[mi][dt][2] * inv); st.w = f2bu(o4[mi][dt][3] * inv);
            *(ushort4*)&Zh[(size_t)(q0 + w * 32 + mi * 16 + l16) * 64 + dt * 16 + quad * 4] = st;
        }
    }
}

// ---------------------------------------------------------------------------
// LayerNorm over H=768, one block per row, fp32 stats. In-place safe.
// ---------------------------------------------------------------------------
__device__ __forceinline__ float to_f(float v)  { return v; }
__device__ __forceinline__ float to_f(bf16_t v) { return b2f(v); }
__device__ __forceinline__ void from_f(float& d, float v)  { d = v; }
__device__ __forceinline__ void from_f(bf16_t& d, float v) { d = f2b(v); }

template <typename TI, typename TO>
__global__ __launch_bounds__(256) void layernorm_kernel(
    const TI* __restrict__ X, const float* __restrict__ w,
    const float* __restrict__ b, TO* __restrict__ out)
{
    const TI* x = X + (size_t)blockIdx.x * 768;
    TO* o = out + (size_t)blockIdx.x * 768;
    int t = threadIdx.x;
    float v[3];
    float s = 0.f, sq = 0.f;
#pragma unroll
    for (int i = 0; i < 3; ++i) {
        v[i] = to_f(x[t + i * 256]);
        s += v[i]; sq += v[i] * v[i];
    }
#pragma unroll
    for (int off = 32; off; off >>= 1) { s += __shfl_xor(s, off); sq += __shfl_xor(sq, off); }
    __shared__ float s1[4], s2[4];
    int wave = t >> 6, lane = t & 63;
    if (lane == 0) { s1[wave] = s; s2[wave] = sq; }
    __syncthreads();
    s  = s1[0] + s1[1] + s1[2] + s1[3];
    sq = s2[0] + s2[1] + s2[2] + s2[3];
    float mu  = s * (1.f / 768.f);
    float var = sq * (1.f / 768.f) - mu * mu;
    float rs  = rsqrtf(var + 1e-5f);
#pragma unroll
    for (int i = 0; i < 3; ++i)
        from_f(o[t + i * 256], (v[i] - mu) * rs * w[t + i * 256] + b[t + i * 256]);
}

// ---------------------------------------------------------------------------
extern "C" void kernel_launch(void* const* d_in, const int* in_sizes, int n_in,
                              void* d_out, int out_size, void* d_ws, size_t ws_size,
                              hipStream_t stream)
{
    const float* X    = (const float*)d_in[0];
    const int*   mask = (const int*)  d_in[1];
    const float* WQ   = (const float*)d_in[2];
    const float* bQ   = (const float*)d_in[3];
    const float* WK   = (const float*)d_in[4];
    const float* bK   = (const float*)d_in[5];
    const float* WV   = (const float*)d_in[6];
    const float* bV   = (const float*)d_in[7];
    const float* WO   = (const float*)d_in[8];
    const float* bO   = (const float*)d_in[9];
    const float* ln1w = (const float*)d_in[10];
    const float* ln1b = (const float*)d_in[11];
    const float* W1   = (const float*)d_in[12];
    const float* b1   = (const float*)d_in[13];
    const float* W2   = (const float*)d_in[14];
    const float* b2   = (const float*)d_in[15];
    const float* ln2w = (const float*)d_in[16];
    const float* ln2b = (const float*)d_in[17];
    float* out = (float*)d_out;

    // ---- workspace (bf16 elems; total 38,539,776 = 77.1 MB) ----
    bf16_t* ws   = (bf16_t*)d_ws;
    bf16_t* Wqkv = ws;                        // [2304][768] (WQt|WKt|WVt)
    bf16_t* WOt  = Wqkv + 1769472;            // [768][768]
    bf16_t* W1t  = WOt + 589824;              // [3072][768]
    bf16_t* W2t  = W1t + 2359296;             // [768][3072]
    float*  bcat = (float*)(W2t + 2359296);   // fp32[2304] (= 4608 bf16)
    bf16_t* Qb   = W2t + 2359296 + 4608;      // packed [8192][768]; Q,K consecutive (EPI 6)
    bf16_t* Kb   = Qb + 6291456;
    bf16_t* Vb   = Kb + 6291456;              // (layout hold)
    bf16_t* Xb   = Vb + 6291456;              // bf16 X (dead after QKV; Y1 alias)
    bf16_t* Vt   = Xb + 6291456;              // per-head V^T [192][64][512], from QKV epilogue
    // aliases (dead-before-write):
    bf16_t* Zb = Qb;   // flash writes Z in-place over Q
    bf16_t* Y1 = Xb;   // O-proj out (Xb dead after QKV gemm)
    bf16_t* X1 = Qb;   // LN1 out (Qb/Z dead after O-proj)
    bf16_t* Hb = Kb;   // FFN mid [8192][3072] = Kb+Vb+Xb+Vt exactly

    // ---- 1. prep ----
    prep_kernel<<<4801, 256, 0, stream>>>(WQ, WK, WV, WO, W1, W2, bQ, bK, bV, X,
                                          Wqkv, WOt, W1t, W2t, bcat, Xb);

    // ---- 2. fused QKV projection -> packed Q/K + transposed Vt ----
    gemm128<6, 128><<<dim3(64, 18), 256, 0, stream>>>(Xb, Wqkv, bcat, Vt, Qb,
                                                      768, 768, 768, 768);

    // ---- 3. flash attention (Q-tile 128), Z in-place over Q ----
    flash_kernel<<<dim3(4, 192), 256, 0, stream>>>(Qb, Kb, Vt, mask, Zb);

    // ---- 4. O-projection + fp32 residual -> Y1, LN1 -> X1 ----
    gemm128<2, 64><<<dim3(64, 12), 256, 0, stream>>>(Zb, WOt, bO, X, Y1,
                                                     768, 768, 768, 768);
    layernorm_kernel<bf16_t, bf16_t><<<8192, 256, 0, stream>>>(Y1, ln1w, ln1b, X1);

    // ---- 5. FFN ----
    gemm128<1, 128><<<dim3(64, 24), 256, 0, stream>>>(X1, W1t, b1, nullptr, Hb,
                                                      768, 768, 768, 3072);
    gemm128<5, 64><<<dim3(64, 12), 256, 0, stream>>>(Hb, W2t, b2, X1, out,
                                                     3072, 3072, 3072, 768);
    layernorm_kernel<float, float><<<8192, 256, 0, stream>>>(out, ln2w, ln2b, out);
}